// Round 13
// baseline (995.277 us; speedup 1.0000x reference)
//
#include <hip/hip_runtime.h>
#include <hip/hip_cooperative_groups.h>

namespace cg = cooperative_groups;

typedef __attribute__((ext_vector_type(8))) short s8v;
typedef __attribute__((ext_vector_type(4))) float f32x4;

#define MFMA16(A,B,C) __builtin_amdgcn_mfma_f32_16x16x32_bf16((A),(B),(C),0,0,0)

__device__ __forceinline__ float b2f(unsigned short s){
  union { unsigned u; float f; } v; v.u = ((unsigned)s) << 16; return v.f;
}
// 2-op bf16 convert (round-half-up)
__device__ __forceinline__ unsigned short f2b(float f){
  union { float f; unsigned u; } v; v.f = f;
  return (unsigned short)((v.u + 0x8000u) >> 16);
}
// packed f32x2 -> bf16x2 (RNE) — compiler can't derive this from the bit-math
__device__ __forceinline__ unsigned cvtpk(float lo, float hi){
  unsigned r;
  asm("v_cvt_pk_bf16_f32 %0, %1, %2" : "=v"(r) : "v"(lo), "v"(hi));
  return r;
}
// silu via v_rcp_f32 (1 ulp) instead of IEEE division sequence
__device__ __forceinline__ float siluf(float x){
  return x * __builtin_amdgcn_rcpf(1.f + __expf(-x));
}

// ================= cooperative CSR build + tmean (ONE dispatch) =============
// Phases are byte-logic-identical to the proven 5-kernel chain; grid.sync()
// replaces dispatch boundaries. Grid 512x256, 7KB LDS, low VGPR -> 2 blocks/CU
// guaranteed co-resident (no deadlock). Fallback path below if launch fails.

__global__ void csr_coop_kernel(const float* __restrict__ t,
                                const float* __restrict__ tw1,
                                const float* __restrict__ tb1,
                                const float* __restrict__ tw2,
                                const float* __restrict__ tb2,
                                float* __restrict__ tmean,
                                const int* __restrict__ src, const int* __restrict__ dst,
                                int* __restrict__ degcur, int* __restrict__ rp,
                                int* __restrict__ bsum,
                                int* __restrict__ csr_src, int* __restrict__ slot_meta,
                                int E, int N){
  cg::grid_group grid = cg::this_grid();
  __shared__ __align__(16) float s1[16*64];
  __shared__ int s[256];
  __shared__ int sb[256];
  __shared__ int so[256];

  const int tid = threadIdx.x;
  const int gidx = blockIdx.x*256 + tid;
  const int gstep = gridDim.x*256;
  int* deg = degcur;
  int* cursor = degcur + N;

  // ---- phase 0: zero deg|cursor (grid-stride); last block computes tmean
  for (int k = gidx; k < 2*N; k += gstep) degcur[k] = 0;
  if (blockIdx.x == gridDim.x - 1){
    const int j = tid & 63;
    const int grp = tid >> 6;
    const float w1 = tw1[j], bb1 = tb1[j];
    #pragma unroll
    for (int b = grp*4; b < grp*4 + 4; ++b)
      s1[b*64 + j] = siluf(t[b] * w1 + bb1);
    __syncthreads();
    if (tid < 64){
      float acc = 0.f;
      for (int b = 0; b < 16; ++b)
        for (int k = 0; k < 64; ++k)
          acc += s1[b*64 + k] * tw2[k*64 + j];
      tmean[j] = tb2[j] + acc * (1.f/16.f);
    }
  }
  grid.sync();

  // ---- phase 1: degree histogram
  for (int i = gidx; i < E; i += gstep) atomicAdd(&deg[dst[i]], 1);
  grid.sync();

  // ---- phase 2: per-1024-chunk scan (slot-padded degrees) -> rp, bsum
  const int nb = (N + 1023) >> 10;
  if (blockIdx.x < nb){
    const int base = blockIdx.x*1024;
    int v[4];
    #pragma unroll
    for (int j = 0; j < 4; ++j){
      int idx = base + tid*4 + j;
      int dv = (idx < N) ? deg[idx] : 0;
      v[j] = (dv + 3) & ~3;
    }
    const int tsum = v[0]+v[1]+v[2]+v[3];
    s[tid] = tsum;
    __syncthreads();
    for (int off = 1; off < 256; off <<= 1){
      int x = (tid >= off) ? s[tid-off] : 0;
      __syncthreads();
      s[tid] += x;
      __syncthreads();
    }
    const int incl = s[tid];
    if (tid == 255) bsum[blockIdx.x] = incl;
    int run = incl - tsum;
    #pragma unroll
    for (int j = 0; j < 4; ++j){
      int idx = base + tid*4 + j;
      if (idx < N) rp[idx] = run;
      run += v[j];
    }
  }
  grid.sync();

  // ---- phase 3: apply bsum exclusive prefix (redundant per-block LDS scan)
  {
    const int v = (tid < nb) ? bsum[tid] : 0;
    sb[tid] = v; so[tid] = v;
    __syncthreads();
    for (int off = 1; off < 256; off <<= 1){
      int x = (tid >= off) ? sb[tid-off] : 0;
      __syncthreads();
      sb[tid] += x;
      __syncthreads();
    }
    for (int i = gidx; i < N; i += gstep){
      const int k = i >> 10;
      rp[i] += sb[k] - so[k];
    }
    if (gidx == 0) rp[N] = sb[nb-1];   // total padded edge count
  }
  grid.sync();

  // ---- phase 4: scatter + slot metadata + tail padding (disjoint writes)
  for (int i = gidx; i < E; i += gstep){
    const int d = dst[i];
    const int pos = rp[d] + atomicAdd(&cursor[d], 1);
    csr_src[pos] = src[i];
  }
  for (int n = gidx; n < N; n += gstep){
    const int base = rp[n];
    const int d = deg[n];
    const int ns = (d + 3) >> 2;
    const int s0 = base >> 2;
    for (int k = 0; k < ns; ++k){
      int c = d - k*4; c = (c > 4) ? 4 : c;
      slot_meta[s0 + k] = n | (c << 28);
    }
    for (int j = d; j < ns*4; ++j) csr_src[base + j] = n;   // self: diff = 0
  }
  if (gidx == 0){
    const int S  = rp[N] >> 2;
    const int S4 = (S + 3) & ~3;
    for (int sI = S; sI < S4; ++sI){
      slot_meta[sI] = 0;                                    // dst 0, cnt 0
      for (int r = 0; r < 4; ++r) csr_src[sI*4 + r] = 0;
    }
  }
}

// ================= fallback chain (proven R12 kernels, unchanged) ===========

__global__ void hist_kernel(const int* __restrict__ dst, int* __restrict__ deg, int E){
  int i = blockIdx.x*256 + threadIdx.x;
  if (i < E) atomicAdd(&deg[dst[i]], 1);
}

__global__ void scan1_kernel(const int* __restrict__ deg, int* __restrict__ rp,
                             int* __restrict__ bsum, int N){
  __shared__ int s[256];
  const int base = blockIdx.x*1024;
  const int t = threadIdx.x;
  int v[4];
  #pragma unroll
  for (int j = 0; j < 4; ++j){
    int idx = base + t*4 + j;
    int dv = (idx < N) ? deg[idx] : 0;
    v[j] = (dv + 3) & ~3;          // padded to slot multiple
  }
  const int tsum = v[0]+v[1]+v[2]+v[3];
  s[t] = tsum;
  __syncthreads();
  for (int off = 1; off < 256; off <<= 1){
    int x = (t >= off) ? s[t-off] : 0;
    __syncthreads();
    s[t] += x;
    __syncthreads();
  }
  const int incl = s[t];
  if (t == 255) bsum[blockIdx.x] = incl;
  int run = incl - tsum;
  #pragma unroll
  for (int j = 0; j < 4; ++j){
    int idx = base + t*4 + j;
    if (idx < N) rp[idx] = run;
    run += v[j];
  }
}

__global__ void scan3_kernel(int* __restrict__ rp, const int* __restrict__ bsum,
                             const int* __restrict__ deg, int N, int nb){
  __shared__ int sb[256];
  __shared__ int so[256];
  const int t = threadIdx.x;
  const int v = (t < nb) ? bsum[t] : 0;
  sb[t] = v; so[t] = v;
  __syncthreads();
  for (int off = 1; off < 256; off <<= 1){
    int x = (t >= off) ? sb[t-off] : 0;
    __syncthreads();
    sb[t] += x;
    __syncthreads();
  }
  int i = blockIdx.x*256 + t;
  if (i < N){
    const int k = i >> 10;
    const int val = rp[i] + (sb[k] - so[k]);   // exclusive prefix of bsum
    rp[i] = val;
    if (i == N-1) rp[N] = val + ((deg[i] + 3) & ~3);   // Epad
  }
}

__global__ void scatter_slot_kernel(const int* __restrict__ src, const int* __restrict__ dst,
                                    const int* __restrict__ rp, int* __restrict__ cursor,
                                    int* __restrict__ csr_src, int* __restrict__ slot_meta,
                                    const int* __restrict__ deg, int E, int N){
  int i = blockIdx.x*256 + threadIdx.x;
  if (i < E){
    const int d = dst[i];
    const int pos = rp[d] + atomicAdd(&cursor[d], 1);
    csr_src[pos] = src[i];
  }
  if (i < N){
    const int base = rp[i];
    const int d = deg[i];
    const int ns = (d + 3) >> 2;
    const int s0 = base >> 2;
    for (int k = 0; k < ns; ++k){
      int c = d - k*4; c = (c > 4) ? 4 : c;
      slot_meta[s0 + k] = i | (c << 28);
    }
    for (int j = d; j < ns*4; ++j) csr_src[base + j] = i;   // self: diff = 0
  }
  if (i == 0){
    const int S  = rp[N] >> 2;
    const int S4 = (S + 3) & ~3;
    for (int s = S; s < S4; ++s){
      slot_meta[s] = 0;                                     // dst 0, cnt 0
      for (int r = 0; r < 4; ++r) csr_src[s*4 + r] = 0;
    }
  }
}

__global__ void tmean_zero_kernel(const float* __restrict__ t,
                                  const float* __restrict__ tw1,
                                  const float* __restrict__ tb1,
                                  const float* __restrict__ tw2,
                                  const float* __restrict__ tb2,
                                  float* __restrict__ tmean,
                                  int* __restrict__ degcur, int n2){
  for (int k = blockIdx.x*256 + threadIdx.x; k < n2; k += gridDim.x*256)
    degcur[k] = 0;
  if (blockIdx.x == 0){
    __shared__ __align__(16) float s1[16*64];
    const int j = threadIdx.x & 63;
    const int grp = threadIdx.x >> 6;     // 0..3, each handles 4 b's
    const float w1 = tw1[j], bb1 = tb1[j];
    #pragma unroll
    for (int b = grp*4; b < grp*4 + 4; ++b)
      s1[b*64 + j] = siluf(t[b] * w1 + bb1);
    __syncthreads();
    if (threadIdx.x < 64){
      float acc = 0.f;
      for (int b = 0; b < 16; ++b)
        for (int k = 0; k < 64; ++k)
          acc += s1[b*64 + k] * tw2[k*64 + j];
      tmean[j] = tb2[j] + acc * (1.f/16.f);
    }
  }
}

// ---------- fused init_h + p12 (R12-proven, unchanged) ----------

__global__ __launch_bounds__(512) void init_p12_kernel(
    const int* __restrict__ z,
    const float* __restrict__ emb,
    const float* __restrict__ tmean,
    const float* __restrict__ ew1, const float* __restrict__ eb1,
    unsigned short* __restrict__ hb,
    float* __restrict__ aggf,
    unsigned short* __restrict__ P1, unsigned short* __restrict__ P2,
    const float* __restrict__ x0, float* __restrict__ xa, int N)
{
  __shared__ __align__(16) short w1a[64*72];
  __shared__ __align__(16) short w1b[64*72];
  __shared__ __align__(16) float b1s[64];

  const int tid = threadIdx.x;
  const float* w1g = ew1;                 // layer 0
  for (int idx = tid; idx < 64*64; idx += 512){
    int k = idx >> 6, n = idx & 63;
    w1a[n*72 + k] = (short)f2b(w1g[k*64 + n]);
    w1b[n*72 + k] = (short)f2b(w1g[(64 + k)*64 + n]);
  }
  if (tid < 64) b1s[tid] = eb1[tid];
  __syncthreads();

  const int lane = tid & 63;
  const int wv = tid >> 6;
  const int q = lane >> 4;
  const int n16 = lane & 15;

  const f32x4 tm0 = *(const f32x4*)(tmean + q*8);
  const f32x4 tm1 = *(const f32x4*)(tmean + q*8 + 4);
  const f32x4 tm2 = *(const f32x4*)(tmean + 32 + q*8);
  const f32x4 tm3 = *(const f32x4*)(tmean + 32 + q*8 + 4);
  const f32x4 zz = {0.f,0.f,0.f,0.f};

  const int ntile = N >> 4;
  const int step = gridDim.x * 8;
  for (int t = blockIdx.x*8 + wv; t < ntile; t += step){
    const int row = t*16 + n16;
    if (lane < 48) xa[t*48 + lane] = x0[t*48 + lane];

    const float* er = emb + (size_t)z[row]*64;   // emb fits L1/L2 (25.6 KB)
    const f32x4 v0 = *(const f32x4*)(er + q*8)          + tm0;
    const f32x4 v1 = *(const f32x4*)(er + q*8 + 4)      + tm1;
    const f32x4 v2 = *(const f32x4*)(er + 32 + q*8)     + tm2;
    const f32x4 v3 = *(const f32x4*)(er + 32 + q*8 + 4) + tm3;

    float* arow = aggf + (size_t)row*64;
    *(f32x4*)(arow + q*8)          = zz;
    *(f32x4*)(arow + q*8 + 4)      = zz;
    *(f32x4*)(arow + 32 + q*8)     = zz;
    *(f32x4*)(arow + 32 + q*8 + 4) = zz;

    s8v a0, a1;
    #pragma unroll
    for (int j = 0; j < 4; ++j){
      a0[j]   = (short)f2b(v0[j]);
      a0[4+j] = (short)f2b(v1[j]);
      a1[j]   = (short)f2b(v2[j]);
      a1[4+j] = (short)f2b(v3[j]);
    }
    *(s8v*)(hb + (size_t)row*64 + q*8)      = a0;
    *(s8v*)(hb + (size_t)row*64 + 32 + q*8) = a1;

    #pragma unroll
    for (int nt = 0; nt < 4; ++nt){
      const s8v* wa = (const s8v*)&w1a[(nt*16 + n16)*72];
      const s8v* wb = (const s8v*)&w1b[(nt*16 + n16)*72];
      f32x4 aA = {0.f,0.f,0.f,0.f};
      aA = MFMA16(a0, wa[q],   aA);
      aA = MFMA16(a1, wa[4+q], aA);
      f32x4 aB = {0.f,0.f,0.f,0.f};
      aB = MFMA16(a0, wb[q],   aB);
      aB = MFMA16(a1, wb[4+q], aB);
      const float bb = b1s[nt*16 + n16];
      #pragma unroll
      for (int r = 0; r < 4; ++r){
        const int o = (t*16 + q*4 + r)*64 + nt*16 + n16;
        P1[o] = f2b(aA[r] + bb);
        P2[o] = f2b(aB[r]);
      }
    }
  }
}

// ---------- edge kernel (R12-proven, unchanged) ----------
// Occupancy lessons (DO NOT REVISIT): 12-16 resident waves/CU is the L2 sweet
// spot; launch_bounds min-waves (R4) and grid 768 (R2) both thrash L2.
// XCD swizzle: -7 µs (R5). LDS stride MUST be 16B multiple (R8).

__global__ __launch_bounds__(512) void edge_tile_kernel(
    const int* __restrict__ rp, const int* __restrict__ csr_src,
    const int* __restrict__ slot_meta,
    const float* __restrict__ x_in, float* __restrict__ x_out,
    const unsigned short* __restrict__ P1, const unsigned short* __restrict__ P2,
    float* __restrict__ aggf,
    const float* __restrict__ ew1,
    const float* __restrict__ ew2, const float* __restrict__ eb2,
    const float* __restrict__ cw1, const float* __restrict__ cb1,
    const float* __restrict__ cw2, const float* __restrict__ cb2,
    int layer, int do_agg, int N)
{
  __shared__ __align__(16) short wT2[64*72];    // e_w2^T [n][k]
  __shared__ __align__(16) short wc1T[64*72];   // c_w1^T
  __shared__ __align__(16) short sc[8][16*72];  // per-wave C->A transpose scratch
  __shared__ __align__(16) float sdiff[8][48];  // [wv][comp*16 + row] (SoA)

  const int tid = threadIdx.x;
  const float* w2g = ew2 + layer*64*64;
  const float* c1g = cw1 + layer*64*64;
  for (int idx = tid; idx < 64*64; idx += 512){
    int k = idx >> 6, n = idx & 63;
    wT2[n*72 + k]  = (short)f2b(w2g[k*64 + n]);
    wc1T[n*72 + k] = (short)f2b(c1g[k*64 + n]);
  }

  const int lane = tid & 63;
  const int wv = tid >> 6;       // 0..7
  const int q = lane >> 4;       // quad 0..3
  const int n16 = lane & 15;
  short* mysc = sc[wv];
  float* mydiff = sdiff[wv];

  const float* wlg = ew1 + layer*129*64 + 128*64;
  float wl_lo[8], wl_hi[8];
  #pragma unroll
  for (int j = 0; j < 8; ++j){
    wl_lo[j] = wlg[q*8 + j];
    wl_hi[j] = wlg[32 + q*8 + j];
  }
  float be2r[4], bc1r[4], cw2r[4];
  #pragma unroll
  for (int nt = 0; nt < 4; ++nt){
    be2r[nt] = eb2[layer*64 + nt*16 + n16];
    bc1r[nt] = cb1[layer*64 + nt*16 + n16];
    cw2r[nt] = cw2[layer*64 + nt*16 + n16];
  }
  const float cb2s = cb2[layer];
  __syncthreads();

  auto tile_compute = [&](int mo, float dx, float dy, float dz,
                          s8v lo1, s8v hi1, s8v lo2, s8v hi2, bool valid){
    const float d2 = dx*dx + dy*dy + dz*dz;
    if (q == 0){ mydiff[n16] = dx; mydiff[16+n16] = dy; mydiff[32+n16] = dz; }

    // MLP1 combine in registers (A-layout); bf16 pack via v_cvt_pk_bf16_f32
    s8v alo, ahi;
    {
      union { unsigned u[4]; s8v s; } ua, ub;
      #pragma unroll
      for (int jp = 0; jp < 4; ++jp){
        const int j0 = 2*jp, j1 = 2*jp + 1;
        const float a0f = siluf(b2f((unsigned short)lo1[j0]) + b2f((unsigned short)lo2[j0]) + d2*wl_lo[j0]);
        const float a1f = siluf(b2f((unsigned short)lo1[j1]) + b2f((unsigned short)lo2[j1]) + d2*wl_lo[j1]);
        ua.u[jp] = cvtpk(a0f, a1f);
        const float b0f = siluf(b2f((unsigned short)hi1[j0]) + b2f((unsigned short)hi2[j0]) + d2*wl_hi[j0]);
        const float b1f = siluf(b2f((unsigned short)hi1[j1]) + b2f((unsigned short)hi2[j1]) + d2*wl_hi[j1]);
        ub.u[jp] = cvtpk(b0f, b1f);
      }
      alo = ua.s; ahi = ub.s;
    }

    // MLP2: (16x64)@(64x64)
    f32x4 acc2[4];
    #pragma unroll
    for (int nt = 0; nt < 4; ++nt){
      const s8v* wb = (const s8v*)&wT2[(nt*16 + n16)*72];
      f32x4 a = {0.f,0.f,0.f,0.f};
      a = MFMA16(alo, wb[q],   a);
      a = MFMA16(ahi, wb[4+q], a);
      acc2[nt] = a;
    }

    const int dn = mo & 0x0FFFFFFF;
    const int cnt = (int)(((unsigned)mo) >> 28);

    float colsum[4] = {0.f,0.f,0.f,0.f};
    #pragma unroll
    for (int nt = 0; nt < 4; ++nt){
      const float bb = be2r[nt];
      #pragma unroll
      for (int r = 0; r < 4; ++r){
        const float mv = siluf(acc2[nt][r] + bb);
        mysc[(q*4 + r)*72 + nt*16 + n16] = (short)cvtpk(mv, mv);  // low half = bf16(mv)
        colsum[nt] += (r < cnt) ? mv : 0.f;
      }
    }
    __builtin_amdgcn_wave_barrier();
    const s8v* srd = (const s8v*)&mysc[n16*72];
    const s8v m0 = srd[q];
    const s8v m1 = srd[4+q];
    __builtin_amdgcn_wave_barrier();

    float pr[4] = {0.f,0.f,0.f,0.f};
    #pragma unroll
    for (int nt = 0; nt < 4; ++nt){
      const s8v* wb = (const s8v*)&wc1T[(nt*16 + n16)*72];
      f32x4 a = {0.f,0.f,0.f,0.f};
      a = MFMA16(m0, wb[q],   a);
      a = MFMA16(m1, wb[4+q], a);
      const float bc = bc1r[nt];
      const float wc2 = cw2r[nt];
      #pragma unroll
      for (int r = 0; r < 4; ++r) pr[r] += siluf(a[r] + bc) * wc2;
    }
    #pragma unroll
    for (int off = 1; off < 16; off <<= 1){
      #pragma unroll
      for (int r = 0; r < 4; ++r) pr[r] += __shfl_xor(pr[r], off, 64);
    }
    const f32x4 dfx = *(const f32x4*)&mydiff[q*4];
    const f32x4 dfy = *(const f32x4*)&mydiff[16 + q*4];
    const f32x4 dfz = *(const f32x4*)&mydiff[32 + q*4];
    float xacc0 = 0.f, xacc1 = 0.f, xacc2 = 0.f;
    #pragma unroll
    for (int r = 0; r < 4; ++r){
      const float cwv = pr[r] + cb2s;     // padded rows: diff = 0 => no effect
      xacc0 += dfx[r] * cwv;
      xacc1 += dfy[r] * cwv;
      xacc2 += dfz[r] * cwv;
    }

    const int dnb = __shfl_xor(dn, 16, 64);
    const bool same = (dnb == dn);
    #pragma unroll
    for (int nt = 0; nt < 4; ++nt){
      const float o = __shfl_xor(colsum[nt], 16, 64);
      if (same) colsum[nt] += o;
    }
    const float o0 = __shfl_xor(xacc0, 16, 64);
    const float o1 = __shfl_xor(xacc1, 16, 64);
    const float o2 = __shfl_xor(xacc2, 16, 64);
    if (same){ xacc0 += o0; xacc1 += o1; xacc2 += o2; }

    const bool writer = (((q & 1) == 0) || !same) && valid;
    if (do_agg && writer){
      #pragma unroll
      for (int nt = 0; nt < 4; ++nt)
        atomicAdd(&aggf[(size_t)dn*64 + nt*16 + n16], colsum[nt]);
    }
    if (writer && n16 < 3){
      const float v = (n16 == 0) ? xacc0 : (n16 == 1) ? xacc1 : xacc2;
      atomicAdd(&x_out[dn*3 + n16], v);
    }
  };

  const int T = (rp[N] + 15) >> 4;      // tiles (tail slots pre-padded)
  const int npair = (T + 1) >> 1;
  const int nwave = gridDim.x * 8;
  for (int pp = blockIdx.x*8 + wv; pp < npair; pp += nwave){
    const int ta = pp*2;
    const int tb = pp*2 + 1;
    const bool vb = (tb < T);
    const int tbb = vb ? tb : ta;       // clamp: duplicate loads, atomics skipped

    const int miA = slot_meta[ta*4 + (n16 >> 2)];
    const int moA = slot_meta[ta*4 + q];
    const int siA = csr_src[ta*16 + n16];
    const int miB = slot_meta[tbb*4 + (n16 >> 2)];
    const int moB = slot_meta[tbb*4 + q];
    const int siB = csr_src[tbb*16 + n16];
    const int diA = miA & 0x0FFFFFFF;
    const int diB = miB & 0x0FFFFFFF;

    const float dxA = x_in[diA*3+0] - x_in[siA*3+0];
    const float dyA = x_in[diA*3+1] - x_in[siA*3+1];
    const float dzA = x_in[diA*3+2] - x_in[siA*3+2];
    const float dxB = x_in[diB*3+0] - x_in[siB*3+0];
    const float dyB = x_in[diB*3+1] - x_in[siB*3+1];
    const float dzB = x_in[diB*3+2] - x_in[siB*3+2];

    const s8v* pdA = (const s8v*)(P1 + (size_t)diA*64);
    const s8v lo1A = pdA[q], hi1A = pdA[4+q];
    const s8v* psA = (const s8v*)(P2 + (size_t)siA*64);
    const s8v lo2A = psA[q], hi2A = psA[4+q];
    const s8v* pdB = (const s8v*)(P1 + (size_t)diB*64);
    const s8v lo1B = pdB[q], hi1B = pdB[4+q];
    const s8v* psB = (const s8v*)(P2 + (size_t)siB*64);   // P2 from SOURCE (siB)
    const s8v lo2B = psB[q], hi2B = psB[4+q];

    tile_compute(moA, dxA, dyA, dzA, lo1A, hi1A, lo2A, hi2A, true);
    tile_compute(moB, dxB, dyB, dzB, lo1B, hi1B, lo2B, hi2B, vb);
  }
}

// ---------- fused node + p12(next layer) (R12-proven, unchanged) ----------

__global__ __launch_bounds__(512) void node_p12_kernel(
    unsigned short* __restrict__ hb,
    float* __restrict__ aggf,
    const float* __restrict__ nw1, const float* __restrict__ nb1,
    const float* __restrict__ nw2, const float* __restrict__ nb2,
    const float* __restrict__ ew1, const float* __restrict__ eb1,
    unsigned short* __restrict__ P1, unsigned short* __restrict__ P2,
    const float* __restrict__ xsrc, float* __restrict__ xdst,
    int layer, int do_zero, int do_h, int N)   // node layer = layer; p12 weights = layer+1
{
  __shared__ __align__(16) short wT1[64*136];
  __shared__ __align__(16) short wT2[64*72];
  __shared__ __align__(16) short w1a[64*72];
  __shared__ __align__(16) short w1b[64*72];
  __shared__ __align__(16) short sc[8][16*72];
  __shared__ __align__(16) float b1s[64];
  __shared__ __align__(16) float b2s[64];
  __shared__ __align__(16) float eb1s[64];

  const int tid = threadIdx.x;
  const float* w1g = nw1 + layer*128*64;
  const float* w2g = nw2 + layer*64*64;
  const float* e1g = ew1 + (layer+1)*129*64;
  for (int idx = tid; idx < 64*128; idx += 512){
    int k = idx >> 6, n = idx & 63;
    wT1[n*136 + k] = (short)f2b(w1g[k*64 + n]);
  }
  for (int idx = tid; idx < 64*64; idx += 512){
    int k = idx >> 6, n = idx & 63;
    wT2[n*72 + k] = (short)f2b(w2g[k*64 + n]);
    w1a[n*72 + k] = (short)f2b(e1g[k*64 + n]);
    w1b[n*72 + k] = (short)f2b(e1g[(64 + k)*64 + n]);
  }
  if (tid < 64){
    b1s[tid]  = nb1[layer*64 + tid];
    b2s[tid]  = nb2[layer*64 + tid];
    eb1s[tid] = eb1[(layer+1)*64 + tid];
  }
  __syncthreads();

  const int lane = tid & 63;
  const int wv = tid >> 6;
  const int q = lane >> 4;
  const int n16 = lane & 15;
  short* mysc = sc[wv];

  const int ntile = N >> 4;
  const int step = gridDim.x * 8;
  for (int t = blockIdx.x*8 + wv; t < ntile; t += step){
    const int row = t*16 + n16;
    const s8v* ph = (const s8v*)(hb + row*64);
    const s8v a0 = ph[q];
    const s8v a1 = ph[4+q];
    const f32x4* pa = (const f32x4*)(aggf + (size_t)row*64);
    const f32x4 u0 = pa[2*q];
    const f32x4 u1 = pa[2*q+1];
    const f32x4 u2 = pa[8+2*q];
    const f32x4 u3 = pa[9+2*q];
    s8v a2, a3;
    #pragma unroll
    for (int j = 0; j < 4; ++j){
      a2[j]   = (short)f2b(u0[j]);
      a2[4+j] = (short)f2b(u1[j]);
      a3[j]   = (short)f2b(u2[j]);
      a3[4+j] = (short)f2b(u3[j]);
    }
    if (do_zero){
      const f32x4 zz = {0.f,0.f,0.f,0.f};
      f32x4* pw = (f32x4*)(aggf + (size_t)row*64);
      pw[2*q] = zz; pw[2*q+1] = zz; pw[8+2*q] = zz; pw[9+2*q] = zz;
    }
    // init next-layer x accumulation buffer (one wave per tile => once)
    if (lane < 48) xdst[t*48 + lane] = xsrc[t*48 + lane];

    // phase 1: g = silu([h|agg] @ n_w1 + b1) -> LDS (C->A transpose)
    #pragma unroll
    for (int nt = 0; nt < 4; ++nt){
      const s8v* wb = (const s8v*)&wT1[(nt*16 + n16)*136];
      f32x4 a = {0.f,0.f,0.f,0.f};
      a = MFMA16(a0, wb[q],    a);
      a = MFMA16(a1, wb[4+q],  a);
      a = MFMA16(a2, wb[8+q],  a);
      a = MFMA16(a3, wb[12+q], a);
      const float bb = b1s[nt*16 + n16];
      #pragma unroll
      for (int r = 0; r < 4; ++r)
        mysc[(q*4 + r)*72 + nt*16 + n16] = (short)f2b(siluf(a[r] + bb));
    }
    __builtin_amdgcn_wave_barrier();
    const s8v* srd = (const s8v*)&mysc[n16*72];
    const s8v g0 = srd[q];
    const s8v g1 = srd[4+q];
    __builtin_amdgcn_wave_barrier();

    // phase 2: h' = bf16(h) + g @ n_w2 + b2 ; store hb (if live) + stash bf16 h'
    #pragma unroll
    for (int nt = 0; nt < 4; ++nt){
      const s8v* wb = (const s8v*)&wT2[(nt*16 + n16)*72];
      f32x4 a = {0.f,0.f,0.f,0.f};
      a = MFMA16(g0, wb[q],   a);
      a = MFMA16(g1, wb[4+q], a);
      const float bb = b2s[nt*16 + n16];
      #pragma unroll
      for (int r = 0; r < 4; ++r){
        const int idx = (t*16 + q*4 + r)*64 + nt*16 + n16;
        const float hv = b2f(hb[idx]) + a[r] + bb;
        const unsigned short hvb = f2b(hv);
        if (do_h) hb[idx] = hvb;
        mysc[(q*4 + r)*72 + nt*16 + n16] = (short)hvb;
      }
    }
    __builtin_amdgcn_wave_barrier();
    const s8v h0 = srd[q];
    const s8v h1 = srd[4+q];
    __builtin_amdgcn_wave_barrier();

    // phase 3: P1/P2 for layer+1 from h' (A-layout)
    #pragma unroll
    for (int nt = 0; nt < 4; ++nt){
      const s8v* wa = (const s8v*)&w1a[(nt*16 + n16)*72];
      const s8v* wb = (const s8v*)&w1b[(nt*16 + n16)*72];
      f32x4 aA = {0.f,0.f,0.f,0.f};
      aA = MFMA16(h0, wa[q],   aA);
      aA = MFMA16(h1, wa[4+q], aA);
      f32x4 aB = {0.f,0.f,0.f,0.f};
      aB = MFMA16(h0, wb[q],   aB);
      aB = MFMA16(h1, wb[4+q], aB);
      const float bb = eb1s[nt*16 + n16];
      #pragma unroll
      for (int r = 0; r < 4; ++r){
        const int o = (t*16 + q*4 + r)*64 + nt*16 + n16;
        P1[o] = f2b(aA[r] + bb);
        P2[o] = f2b(aB[r]);
      }
    }
  }
}

// ---------- launch ----------

extern "C" void kernel_launch(void* const* d_in, const int* in_sizes, int n_in,
                              void* d_out, int out_size, void* d_ws, size_t ws_size,
                              hipStream_t stream)
{
  // Inputs are fp32 (established R4..R12). Read d_in directly.
  const float* x0   = (const float*)d_in[0];
  const int*   z    = (const int*)d_in[1];
  const float* tc   = (const float*)d_in[2];
  const int*   ei   = (const int*)d_in[3];
  const float* embc = (const float*)d_in[4];
  const float* tw1c = (const float*)d_in[5];
  const float* tb1c = (const float*)d_in[6];
  const float* tw2c = (const float*)d_in[7];
  const float* tb2c = (const float*)d_in[8];
  const float* ew1c = (const float*)d_in[9];
  const float* eb1c = (const float*)d_in[10];
  const float* ew2c = (const float*)d_in[11];
  const float* eb2c = (const float*)d_in[12];
  const float* cw1c = (const float*)d_in[13];
  const float* cb1c = (const float*)d_in[14];
  const float* cw2c = (const float*)d_in[15];
  const float* cb2c = (const float*)d_in[16];
  const float* nw1c = (const float*)d_in[17];
  const float* nb1c = (const float*)d_in[18];
  const float* nw2c = (const float*)d_in[19];
  const float* nb2c = (const float*)d_in[20];

  const int N = in_sizes[1];
  int E = in_sizes[3] / 2;
  const int* srcp = ei;
  const int* dstp = ei + E;

  char* p = (char*)d_ws;
  auto alloc = [&](size_t bytes) -> void* {
    void* r = (void*)p; p += (bytes + 255) & ~(size_t)255; return r;
  };
  unsigned short* hbuf = (unsigned short*)alloc((size_t)N*64*2);
  float* aggf          = (float*)alloc((size_t)N*64*4);     // fp32 (atomic accum)
  unsigned short* P1   = (unsigned short*)alloc((size_t)N*64*2);
  unsigned short* P2   = (unsigned short*)alloc((size_t)N*64*2);
  float* xa            = (float*)alloc((size_t)N*3*4);
  float* xb            = (float*)alloc((size_t)N*3*4);
  float* tmean         = (float*)alloc(64*4);
  int*   degcur        = (int*)alloc((size_t)2*N*4);   // deg | cursor
  int*   deg           = degcur;
  int*   cursor        = degcur + N;
  int*   rowp          = (int*)alloc((size_t)(N+1)*4); // slot-padded prefix
  int*   bsum          = (int*)alloc(256*4);
  int*   csr_src       = (int*)alloc(((size_t)E + 3*(size_t)N + 64)*4);
  int*   slot_meta     = (int*)alloc(((size_t)E/4 + (size_t)N + 16)*4);

  int Nv = N;
  // ---- cooperative CSR+tmean (1 dispatch); proven 5-dispatch fallback ----
  void* cargs[] = { (void*)&tc, (void*)&tw1c, (void*)&tb1c, (void*)&tw2c, (void*)&tb2c,
                    (void*)&tmean, (void*)&srcp, (void*)&dstp, (void*)&degcur,
                    (void*)&rowp, (void*)&bsum, (void*)&csr_src, (void*)&slot_meta,
                    (void*)&E, (void*)&Nv };
  hipError_t cerr = hipLaunchCooperativeKernel((void*)csr_coop_kernel,
                        dim3(512), dim3(256), cargs, 0, stream);
  if (cerr != hipSuccess){
    (void)hipGetLastError();   // clear sticky error; use proven chain
    tmean_zero_kernel<<<512, 256, 0, stream>>>(tc, tw1c, tb1c, tw2c, tb2c,
                                               tmean, degcur, 2*N);
    hist_kernel<<<(E + 255)/256, 256, 0, stream>>>(dstp, deg, E);
    const int nb = (N + 1023)/1024;
    scan1_kernel<<<nb, 256, 0, stream>>>(deg, rowp, bsum, N);
    scan3_kernel<<<(N + 255)/256, 256, 0, stream>>>(rowp, bsum, deg, N, nb);
    scatter_slot_kernel<<<(E + 255)/256, 256, 0, stream>>>(srcp, dstp, rowp, cursor,
                                                           csr_src, slot_meta, deg, E, N);
  }

  // fused: h init (hb) + aggf zero + x0->xa copy + layer-0 P1/P2
  init_p12_kernel<<<512, 512, 0, stream>>>(z, embc, tmean, ew1c, eb1c,
                                           hbuf, aggf, P1, P2, x0, xa, N);

  const float* xc = x0;
  float* xnexts[3] = {xa, xb, (float*)d_out};
  for (int l = 0; l < 3; ++l){
    float* xout = xnexts[l];
    edge_tile_kernel<<<1024, 512, 0, stream>>>(rowp, csr_src, slot_meta, xc, xout,
        P1, P2, aggf,
        ew1c, ew2c, eb2c, cw1c, cb1c, cw2c, cb2c, l, (l < 2) ? 1 : 0, N);
    if (l < 2)
      node_p12_kernel<<<512, 512, 0, stream>>>(hbuf, aggf,
          nw1c, nb1c, nw2c, nb2c, ew1c, eb1c, P1, P2,
          xout, xnexts[l+1], l, (l == 0) ? 1 : 0, (l == 0) ? 1 : 0, N);
    xc = xout;
  }
}

// Round 14
// 752.269 us; speedup vs baseline: 1.3230x; 1.3230x over previous
//
#include <hip/hip_runtime.h>

typedef __attribute__((ext_vector_type(8))) short s8v;
typedef __attribute__((ext_vector_type(4))) float f32x4;

#define MFMA16(A,B,C) __builtin_amdgcn_mfma_f32_16x16x32_bf16((A),(B),(C),0,0,0)

__device__ __forceinline__ float b2f(unsigned short s){
  union { unsigned u; float f; } v; v.u = ((unsigned)s) << 16; return v.f;
}
// 2-op bf16 convert (round-half-up)
__device__ __forceinline__ unsigned short f2b(float f){
  union { float f; unsigned u; } v; v.f = f;
  return (unsigned short)((v.u + 0x8000u) >> 16);
}
// packed f32x2 -> bf16x2 (RNE) — compiler can't derive this from the bit-math
__device__ __forceinline__ unsigned cvtpk(float lo, float hi){
  unsigned r;
  asm("v_cvt_pk_bf16_f32 %0, %1, %2" : "=v"(r) : "v"(lo), "v"(hi));
  return r;
}
// silu via v_rcp_f32 (1 ulp) instead of IEEE division sequence
__device__ __forceinline__ float siluf(float x){
  return x * __builtin_amdgcn_rcpf(1.f + __expf(-x));
}

// ---------- CSR build (rebuilt every call — workspace is re-poisoned between
// iterations; R5 hash experiment proved cross-call caching impossible).
// R13 lesson: do NOT fuse this chain into a cooperative kernel — grid.sync()
// under graph capture costs ~80 µs per barrier (coop version ran 370 µs at
// 0.4% VALUBusy vs ~60 µs total for the 5-dispatch chain).

__global__ void hist_kernel(const int* __restrict__ dst, int* __restrict__ deg, int E){
  int i = blockIdx.x*256 + threadIdx.x;
  if (i < E) atomicAdd(&deg[dst[i]], 1);
}

__global__ void scan1_kernel(const int* __restrict__ deg, int* __restrict__ rp,
                             int* __restrict__ bsum, int N){
  __shared__ int s[256];
  const int base = blockIdx.x*1024;
  const int t = threadIdx.x;
  int v[4];
  #pragma unroll
  for (int j = 0; j < 4; ++j){
    int idx = base + t*4 + j;
    int dv = (idx < N) ? deg[idx] : 0;
    v[j] = (dv + 3) & ~3;          // padded to slot multiple
  }
  const int tsum = v[0]+v[1]+v[2]+v[3];
  s[t] = tsum;
  __syncthreads();
  for (int off = 1; off < 256; off <<= 1){
    int x = (t >= off) ? s[t-off] : 0;
    __syncthreads();
    s[t] += x;
    __syncthreads();
  }
  const int incl = s[t];
  if (t == 255) bsum[blockIdx.x] = incl;
  int run = incl - tsum;
  #pragma unroll
  for (int j = 0; j < 4; ++j){
    int idx = base + t*4 + j;
    if (idx < N) rp[idx] = run;
    run += v[j];
  }
}

// scan2 merged in: every block redundantly prefix-sums bsum (<=256 entries)
// in LDS — saves one dispatch vs a separate scan2.
__global__ void scan3_kernel(int* __restrict__ rp, const int* __restrict__ bsum,
                             const int* __restrict__ deg, int N, int nb){
  __shared__ int sb[256];
  __shared__ int so[256];
  const int t = threadIdx.x;
  const int v = (t < nb) ? bsum[t] : 0;
  sb[t] = v; so[t] = v;
  __syncthreads();
  for (int off = 1; off < 256; off <<= 1){
    int x = (t >= off) ? sb[t-off] : 0;
    __syncthreads();
    sb[t] += x;
    __syncthreads();
  }
  int i = blockIdx.x*256 + t;
  if (i < N){
    const int k = i >> 10;
    const int val = rp[i] + (sb[k] - so[k]);   // exclusive prefix of bsum
    rp[i] = val;
    if (i == N-1) rp[N] = val + ((deg[i] + 3) & ~3);   // Epad
  }
}

// scatter + slot_build merged (disjoint writes; both only need rp/deg).
__global__ void scatter_slot_kernel(const int* __restrict__ src, const int* __restrict__ dst,
                                    const int* __restrict__ rp, int* __restrict__ cursor,
                                    int* __restrict__ csr_src, int* __restrict__ slot_meta,
                                    const int* __restrict__ deg, int E, int N){
  int i = blockIdx.x*256 + threadIdx.x;
  if (i < E){
    const int d = dst[i];
    const int pos = rp[d] + atomicAdd(&cursor[d], 1);
    csr_src[pos] = src[i];
  }
  if (i < N){
    const int base = rp[i];
    const int d = deg[i];
    const int ns = (d + 3) >> 2;
    const int s0 = base >> 2;
    for (int k = 0; k < ns; ++k){
      int c = d - k*4; c = (c > 4) ? 4 : c;
      slot_meta[s0 + k] = i | (c << 28);
    }
    for (int j = d; j < ns*4; ++j) csr_src[base + j] = i;   // self: diff = 0
  }
  if (i == 0){
    const int S  = rp[N] >> 2;
    const int S4 = (S + 3) & ~3;
    for (int s = S; s < S4; ++s){
      slot_meta[s] = 0;                                     // dst 0, cnt 0
      for (int r = 0; r < 4; ++r) csr_src[s*4 + r] = 0;
    }
  }
}

// ---------- prologue: tmean (block 0) + degcur zeroing (all blocks) ----------

__global__ void tmean_zero_kernel(const float* __restrict__ t,
                                  const float* __restrict__ tw1,
                                  const float* __restrict__ tb1,
                                  const float* __restrict__ tw2,
                                  const float* __restrict__ tb2,
                                  float* __restrict__ tmean,
                                  int* __restrict__ degcur, int n2){
  for (int k = blockIdx.x*256 + threadIdx.x; k < n2; k += gridDim.x*256)
    degcur[k] = 0;
  if (blockIdx.x == 0){
    __shared__ __align__(16) float s1[16*64];
    const int j = threadIdx.x & 63;
    const int grp = threadIdx.x >> 6;     // 0..3, each handles 4 b's
    const float w1 = tw1[j], bb1 = tb1[j];
    #pragma unroll
    for (int b = grp*4; b < grp*4 + 4; ++b)
      s1[b*64 + j] = siluf(t[b] * w1 + bb1);
    __syncthreads();
    if (threadIdx.x < 64){
      float acc = 0.f;
      for (int b = 0; b < 16; ++b)
        for (int k = 0; k < 64; ++k)
          acc += s1[b*64 + k] * tw2[k*64 + j];
      tmean[j] = tb2[j] + acc * (1.f/16.f);
    }
  }
}

// ---------- fused init_h + p12: tile-based ----------
// Per 16-row tile: h = emb[z] + tmean -> hb (bf16 only — the fp32 hf buffer
// is gone: the h residual chain is carried in bf16, which every MFMA consumer
// already sees), aggf zeroed, x0->xa copied, layer-0 P1/P2 by MFMA directly.
// LDS stride 72 shorts = 144 B = 9*16 — KEEP 16B-multiple for b128 reads.

__global__ __launch_bounds__(512) void init_p12_kernel(
    const int* __restrict__ z,
    const float* __restrict__ emb,
    const float* __restrict__ tmean,
    const float* __restrict__ ew1, const float* __restrict__ eb1,
    unsigned short* __restrict__ hb,
    float* __restrict__ aggf,
    unsigned short* __restrict__ P1, unsigned short* __restrict__ P2,
    const float* __restrict__ x0, float* __restrict__ xa, int N)
{
  __shared__ __align__(16) short w1a[64*72];
  __shared__ __align__(16) short w1b[64*72];
  __shared__ __align__(16) float b1s[64];

  const int tid = threadIdx.x;
  const float* w1g = ew1;                 // layer 0
  for (int idx = tid; idx < 64*64; idx += 512){
    int k = idx >> 6, n = idx & 63;
    w1a[n*72 + k] = (short)f2b(w1g[k*64 + n]);
    w1b[n*72 + k] = (short)f2b(w1g[(64 + k)*64 + n]);
  }
  if (tid < 64) b1s[tid] = eb1[tid];
  __syncthreads();

  const int lane = tid & 63;
  const int wv = tid >> 6;
  const int q = lane >> 4;
  const int n16 = lane & 15;

  // loop-invariant tmean slices for this lane's columns
  const f32x4 tm0 = *(const f32x4*)(tmean + q*8);
  const f32x4 tm1 = *(const f32x4*)(tmean + q*8 + 4);
  const f32x4 tm2 = *(const f32x4*)(tmean + 32 + q*8);
  const f32x4 tm3 = *(const f32x4*)(tmean + 32 + q*8 + 4);
  const f32x4 zz = {0.f,0.f,0.f,0.f};

  const int ntile = N >> 4;
  const int step = gridDim.x * 8;
  for (int t = blockIdx.x*8 + wv; t < ntile; t += step){
    const int row = t*16 + n16;
    if (lane < 48) xa[t*48 + lane] = x0[t*48 + lane];

    const float* er = emb + (size_t)z[row]*64;   // emb fits L1/L2 (25.6 KB)
    const f32x4 v0 = *(const f32x4*)(er + q*8)          + tm0;
    const f32x4 v1 = *(const f32x4*)(er + q*8 + 4)      + tm1;
    const f32x4 v2 = *(const f32x4*)(er + 32 + q*8)     + tm2;
    const f32x4 v3 = *(const f32x4*)(er + 32 + q*8 + 4) + tm3;

    float* arow = aggf + (size_t)row*64;
    *(f32x4*)(arow + q*8)          = zz;
    *(f32x4*)(arow + q*8 + 4)      = zz;
    *(f32x4*)(arow + 32 + q*8)     = zz;
    *(f32x4*)(arow + 32 + q*8 + 4) = zz;

    s8v a0, a1;
    #pragma unroll
    for (int j = 0; j < 4; ++j){
      a0[j]   = (short)f2b(v0[j]);
      a0[4+j] = (short)f2b(v1[j]);
      a1[j]   = (short)f2b(v2[j]);
      a1[4+j] = (short)f2b(v3[j]);
    }
    *(s8v*)(hb + (size_t)row*64 + q*8)      = a0;
    *(s8v*)(hb + (size_t)row*64 + 32 + q*8) = a1;

    // P1/P2 (layer 0) from h (A-layout fragments already in registers)
    #pragma unroll
    for (int nt = 0; nt < 4; ++nt){
      const s8v* wa = (const s8v*)&w1a[(nt*16 + n16)*72];
      const s8v* wb = (const s8v*)&w1b[(nt*16 + n16)*72];
      f32x4 aA = {0.f,0.f,0.f,0.f};
      aA = MFMA16(a0, wa[q],   aA);
      aA = MFMA16(a1, wa[4+q], aA);
      f32x4 aB = {0.f,0.f,0.f,0.f};
      aB = MFMA16(a0, wb[q],   aB);
      aB = MFMA16(a1, wb[4+q], aB);
      const float bb = b1s[nt*16 + n16];
      #pragma unroll
      for (int r = 0; r < 4; ++r){
        const int o = (t*16 + q*4 + r)*64 + nt*16 + n16;
        P1[o] = f2b(aA[r] + bb);
        P2[o] = f2b(aB[r]);
      }
    }
  }
}

// ---------- edge kernel: dense 16-row tiles, TWO tiles per iteration ----------
// R12-proven 158.6 µs body (stride 72, cvtpk mysc store).
// Occupancy lessons (DO NOT REVISIT): 12-16 resident waves/CU is the L2 sweet
// spot; launch_bounds min-waves (R4) and grid 768 (R2) both thrash L2.
// XCD swizzle: -7 µs (R5). CSR hash-cache: dead (R5). LDS stride MUST be a
// multiple of 8 shorts (16 B) for the b128 row reads (R8). P2 gathers from
// the SOURCE node (R8/R9 psB typo lesson: diff reverts vs last PASSING src).

__global__ __launch_bounds__(512) void edge_tile_kernel(
    const int* __restrict__ rp, const int* __restrict__ csr_src,
    const int* __restrict__ slot_meta,
    const float* __restrict__ x_in, float* __restrict__ x_out,
    const unsigned short* __restrict__ P1, const unsigned short* __restrict__ P2,
    float* __restrict__ aggf,
    const float* __restrict__ ew1,
    const float* __restrict__ ew2, const float* __restrict__ eb2,
    const float* __restrict__ cw1, const float* __restrict__ cb1,
    const float* __restrict__ cw2, const float* __restrict__ cb2,
    int layer, int do_agg, int N)
{
  __shared__ __align__(16) short wT2[64*72];    // e_w2^T [n][k]
  __shared__ __align__(16) short wc1T[64*72];   // c_w1^T
  __shared__ __align__(16) short sc[8][16*72];  // per-wave C->A transpose scratch
  __shared__ __align__(16) float sdiff[8][48];  // [wv][comp*16 + row] (SoA)

  const int tid = threadIdx.x;
  const float* w2g = ew2 + layer*64*64;
  const float* c1g = cw1 + layer*64*64;
  for (int idx = tid; idx < 64*64; idx += 512){
    int k = idx >> 6, n = idx & 63;
    wT2[n*72 + k]  = (short)f2b(w2g[k*64 + n]);
    wc1T[n*72 + k] = (short)f2b(c1g[k*64 + n]);
  }

  const int lane = tid & 63;
  const int wv = tid >> 6;       // 0..7
  const int q = lane >> 4;       // quad 0..3
  const int n16 = lane & 15;
  short* mysc = sc[wv];
  float* mydiff = sdiff[wv];

  // per-lane loop-invariant constants in registers
  const float* wlg = ew1 + layer*129*64 + 128*64;
  float wl_lo[8], wl_hi[8];
  #pragma unroll
  for (int j = 0; j < 8; ++j){
    wl_lo[j] = wlg[q*8 + j];
    wl_hi[j] = wlg[32 + q*8 + j];
  }
  float be2r[4], bc1r[4], cw2r[4];
  #pragma unroll
  for (int nt = 0; nt < 4; ++nt){
    be2r[nt] = eb2[layer*64 + nt*16 + n16];
    bc1r[nt] = cb1[layer*64 + nt*16 + n16];
    cw2r[nt] = cw2[layer*64 + nt*16 + n16];
  }
  const float cb2s = cb2[layer];
  __syncthreads();

  // per-tile compute (phases identical to the proven R1/R3 body)
  auto tile_compute = [&](int mo, float dx, float dy, float dz,
                          s8v lo1, s8v hi1, s8v lo2, s8v hi2, bool valid){
    const float d2 = dx*dx + dy*dy + dz*dz;
    if (q == 0){ mydiff[n16] = dx; mydiff[16+n16] = dy; mydiff[32+n16] = dz; }

    // MLP1 combine in registers (A-layout); bf16 pack via v_cvt_pk_bf16_f32
    s8v alo, ahi;
    {
      union { unsigned u[4]; s8v s; } ua, ub;
      #pragma unroll
      for (int jp = 0; jp < 4; ++jp){
        const int j0 = 2*jp, j1 = 2*jp + 1;
        const float a0f = siluf(b2f((unsigned short)lo1[j0]) + b2f((unsigned short)lo2[j0]) + d2*wl_lo[j0]);
        const float a1f = siluf(b2f((unsigned short)lo1[j1]) + b2f((unsigned short)lo2[j1]) + d2*wl_lo[j1]);
        ua.u[jp] = cvtpk(a0f, a1f);
        const float b0f = siluf(b2f((unsigned short)hi1[j0]) + b2f((unsigned short)hi2[j0]) + d2*wl_hi[j0]);
        const float b1f = siluf(b2f((unsigned short)hi1[j1]) + b2f((unsigned short)hi2[j1]) + d2*wl_hi[j1]);
        ub.u[jp] = cvtpk(b0f, b1f);
      }
      alo = ua.s; ahi = ub.s;
    }

    // MLP2: (16x64)@(64x64)
    f32x4 acc2[4];
    #pragma unroll
    for (int nt = 0; nt < 4; ++nt){
      const s8v* wb = (const s8v*)&wT2[(nt*16 + n16)*72];
      f32x4 a = {0.f,0.f,0.f,0.f};
      a = MFMA16(alo, wb[q],   a);
      a = MFMA16(ahi, wb[4+q], a);
      acc2[nt] = a;
    }

    // output side: this lane owns rows q*4+r => one slot
    const int dn = mo & 0x0FFFFFFF;
    const int cnt = (int)(((unsigned)mo) >> 28);

    float colsum[4] = {0.f,0.f,0.f,0.f};
    #pragma unroll
    for (int nt = 0; nt < 4; ++nt){
      const float bb = be2r[nt];
      #pragma unroll
      for (int r = 0; r < 4; ++r){
        const float mv = siluf(acc2[nt][r] + bb);
        mysc[(q*4 + r)*72 + nt*16 + n16] = (short)cvtpk(mv, mv);  // low half = bf16(mv)
        colsum[nt] += (r < cnt) ? mv : 0.f;
      }
    }
    __builtin_amdgcn_wave_barrier();
    const s8v* srd = (const s8v*)&mysc[n16*72];
    const s8v m0 = srd[q];
    const s8v m1 = srd[4+q];
    __builtin_amdgcn_wave_barrier();

    // coord MLP: silu(m@c_w1+b) @ c_w2 + b
    float pr[4] = {0.f,0.f,0.f,0.f};
    #pragma unroll
    for (int nt = 0; nt < 4; ++nt){
      const s8v* wb = (const s8v*)&wc1T[(nt*16 + n16)*72];
      f32x4 a = {0.f,0.f,0.f,0.f};
      a = MFMA16(m0, wb[q],   a);
      a = MFMA16(m1, wb[4+q], a);
      const float bc = bc1r[nt];
      const float wc2 = cw2r[nt];
      #pragma unroll
      for (int r = 0; r < 4; ++r) pr[r] += siluf(a[r] + bc) * wc2;
    }
    #pragma unroll
    for (int off = 1; off < 16; off <<= 1){
      #pragma unroll
      for (int r = 0; r < 4; ++r) pr[r] += __shfl_xor(pr[r], off, 64);
    }
    const f32x4 dfx = *(const f32x4*)&mydiff[q*4];
    const f32x4 dfy = *(const f32x4*)&mydiff[16 + q*4];
    const f32x4 dfz = *(const f32x4*)&mydiff[32 + q*4];
    float xacc0 = 0.f, xacc1 = 0.f, xacc2 = 0.f;
    #pragma unroll
    for (int r = 0; r < 4; ++r){
      const float cwv = pr[r] + cb2s;     // padded rows: diff = 0 => no effect
      xacc0 += dfx[r] * cwv;
      xacc1 += dfy[r] * cwv;
      xacc2 += dfz[r] * cwv;
    }

    // merge slot pairs (q, q^1) when same dst, then atomics
    const int dnb = __shfl_xor(dn, 16, 64);
    const bool same = (dnb == dn);
    #pragma unroll
    for (int nt = 0; nt < 4; ++nt){
      const float o = __shfl_xor(colsum[nt], 16, 64);
      if (same) colsum[nt] += o;
    }
    const float o0 = __shfl_xor(xacc0, 16, 64);
    const float o1 = __shfl_xor(xacc1, 16, 64);
    const float o2 = __shfl_xor(xacc2, 16, 64);
    if (same){ xacc0 += o0; xacc1 += o1; xacc2 += o2; }

    const bool writer = (((q & 1) == 0) || !same) && valid;
    if (do_agg && writer){
      #pragma unroll
      for (int nt = 0; nt < 4; ++nt)
        atomicAdd(&aggf[(size_t)dn*64 + nt*16 + n16], colsum[nt]);
    }
    if (writer && n16 < 3){
      const float v = (n16 == 0) ? xacc0 : (n16 == 1) ? xacc1 : xacc2;
      atomicAdd(&x_out[dn*3 + n16], v);
    }
  };

  const int T = (rp[N] + 15) >> 4;      // tiles (tail slots pre-padded)
  const int npair = (T + 1) >> 1;
  const int nwave = gridDim.x * 8;
  for (int pp = blockIdx.x*8 + wv; pp < npair; pp += nwave){
    const int ta = pp*2;
    const int tb = pp*2 + 1;
    const bool vb = (tb < T);
    const int tbb = vb ? tb : ta;       // clamp: duplicate loads, atomics skipped

    // ---- all loads for BOTH tiles issue here
    const int miA = slot_meta[ta*4 + (n16 >> 2)];
    const int moA = slot_meta[ta*4 + q];
    const int siA = csr_src[ta*16 + n16];
    const int miB = slot_meta[tbb*4 + (n16 >> 2)];
    const int moB = slot_meta[tbb*4 + q];
    const int siB = csr_src[tbb*16 + n16];
    const int diA = miA & 0x0FFFFFFF;
    const int diB = miB & 0x0FFFFFFF;

    const float dxA = x_in[diA*3+0] - x_in[siA*3+0];
    const float dyA = x_in[diA*3+1] - x_in[siA*3+1];
    const float dzA = x_in[diA*3+2] - x_in[siA*3+2];
    const float dxB = x_in[diB*3+0] - x_in[siB*3+0];
    const float dyB = x_in[diB*3+1] - x_in[siB*3+1];
    const float dzB = x_in[diB*3+2] - x_in[siB*3+2];

    const s8v* pdA = (const s8v*)(P1 + (size_t)diA*64);
    const s8v lo1A = pdA[q], hi1A = pdA[4+q];
    const s8v* psA = (const s8v*)(P2 + (size_t)siA*64);
    const s8v lo2A = psA[q], hi2A = psA[4+q];
    const s8v* pdB = (const s8v*)(P1 + (size_t)diB*64);
    const s8v lo1B = pdB[q], hi1B = pdB[4+q];
    const s8v* psB = (const s8v*)(P2 + (size_t)siB*64);   // P2 from SOURCE (siB)
    const s8v lo2B = psB[q], hi2B = psB[4+q];

    tile_compute(moA, dxA, dyA, dzA, lo1A, hi1A, lo2A, hi2A, true);
    tile_compute(moB, dxB, dyB, dzB, lo1B, hi1B, lo2B, hi2B, vb);
  }
}

// ---------- fused node + p12(next layer) ----------
// h' = h + MLP([h|agg]) with the residual chain in bf16 (hf eliminated);
// then P1/P2 for layer+1 from h'.  Also fused:
//  - re-zero aggf rows after reading (replaces the layer-1 memset)
//  - copy xsrc -> xdst (flat 48 floats/tile) = init of next edge accumulation
//  - do_h==0 (last node layer): skip dead hb stores — h never read again

__global__ __launch_bounds__(512) void node_p12_kernel(
    unsigned short* __restrict__ hb,
    float* __restrict__ aggf,
    const float* __restrict__ nw1, const float* __restrict__ nb1,
    const float* __restrict__ nw2, const float* __restrict__ nb2,
    const float* __restrict__ ew1, const float* __restrict__ eb1,
    unsigned short* __restrict__ P1, unsigned short* __restrict__ P2,
    const float* __restrict__ xsrc, float* __restrict__ xdst,
    int layer, int do_zero, int do_h, int N)   // node layer = layer; p12 weights = layer+1
{
  __shared__ __align__(16) short wT1[64*136];
  __shared__ __align__(16) short wT2[64*72];
  __shared__ __align__(16) short w1a[64*72];
  __shared__ __align__(16) short w1b[64*72];
  __shared__ __align__(16) short sc[8][16*72];
  __shared__ __align__(16) float b1s[64];
  __shared__ __align__(16) float b2s[64];
  __shared__ __align__(16) float eb1s[64];

  const int tid = threadIdx.x;
  const float* w1g = nw1 + layer*128*64;
  const float* w2g = nw2 + layer*64*64;
  const float* e1g = ew1 + (layer+1)*129*64;
  for (int idx = tid; idx < 64*128; idx += 512){
    int k = idx >> 6, n = idx & 63;
    wT1[n*136 + k] = (short)f2b(w1g[k*64 + n]);
  }
  for (int idx = tid; idx < 64*64; idx += 512){
    int k = idx >> 6, n = idx & 63;
    wT2[n*72 + k] = (short)f2b(w2g[k*64 + n]);
    w1a[n*72 + k] = (short)f2b(e1g[k*64 + n]);
    w1b[n*72 + k] = (short)f2b(e1g[(64 + k)*64 + n]);
  }
  if (tid < 64){
    b1s[tid]  = nb1[layer*64 + tid];
    b2s[tid]  = nb2[layer*64 + tid];
    eb1s[tid] = eb1[(layer+1)*64 + tid];
  }
  __syncthreads();

  const int lane = tid & 63;
  const int wv = tid >> 6;
  const int q = lane >> 4;
  const int n16 = lane & 15;
  short* mysc = sc[wv];

  const int ntile = N >> 4;
  const int step = gridDim.x * 8;
  for (int t = blockIdx.x*8 + wv; t < ntile; t += step){
    const int row = t*16 + n16;
    const s8v* ph = (const s8v*)(hb + row*64);
    const s8v a0 = ph[q];
    const s8v a1 = ph[4+q];
    const f32x4* pa = (const f32x4*)(aggf + (size_t)row*64);
    const f32x4 u0 = pa[2*q];
    const f32x4 u1 = pa[2*q+1];
    const f32x4 u2 = pa[8+2*q];
    const f32x4 u3 = pa[9+2*q];
    s8v a2, a3;
    #pragma unroll
    for (int j = 0; j < 4; ++j){
      a2[j]   = (short)f2b(u0[j]);
      a2[4+j] = (short)f2b(u1[j]);
      a3[j]   = (short)f2b(u2[j]);
      a3[4+j] = (short)f2b(u3[j]);
    }
    if (do_zero){
      const f32x4 zz = {0.f,0.f,0.f,0.f};
      f32x4* pw = (f32x4*)(aggf + (size_t)row*64);
      pw[2*q] = zz; pw[2*q+1] = zz; pw[8+2*q] = zz; pw[9+2*q] = zz;
    }
    // init next-layer x accumulation buffer (one wave per tile => once)
    if (lane < 48) xdst[t*48 + lane] = xsrc[t*48 + lane];

    // phase 1: g = silu([h|agg] @ n_w1 + b1) -> LDS (C->A transpose)
    #pragma unroll
    for (int nt = 0; nt < 4; ++nt){
      const s8v* wb = (const s8v*)&wT1[(nt*16 + n16)*136];
      f32x4 a = {0.f,0.f,0.f,0.f};
      a = MFMA16(a0, wb[q],    a);
      a = MFMA16(a1, wb[4+q],  a);
      a = MFMA16(a2, wb[8+q],  a);
      a = MFMA16(a3, wb[12+q], a);
      const float bb = b1s[nt*16 + n16];
      #pragma unroll
      for (int r = 0; r < 4; ++r)
        mysc[(q*4 + r)*72 + nt*16 + n16] = (short)f2b(siluf(a[r] + bb));
    }
    __builtin_amdgcn_wave_barrier();
    const s8v* srd = (const s8v*)&mysc[n16*72];
    const s8v g0 = srd[q];
    const s8v g1 = srd[4+q];
    __builtin_amdgcn_wave_barrier();

    // phase 2: h' = bf16(h) + g @ n_w2 + b2 ; store hb (if live) + stash bf16 h'
    // (reads hb[idx] BEFORE overwriting — tile rows are wave-exclusive)
    #pragma unroll
    for (int nt = 0; nt < 4; ++nt){
      const s8v* wb = (const s8v*)&wT2[(nt*16 + n16)*72];
      f32x4 a = {0.f,0.f,0.f,0.f};
      a = MFMA16(g0, wb[q],   a);
      a = MFMA16(g1, wb[4+q], a);
      const float bb = b2s[nt*16 + n16];
      #pragma unroll
      for (int r = 0; r < 4; ++r){
        const int idx = (t*16 + q*4 + r)*64 + nt*16 + n16;
        const float hv = b2f(hb[idx]) + a[r] + bb;
        const unsigned short hvb = f2b(hv);
        if (do_h) hb[idx] = hvb;
        mysc[(q*4 + r)*72 + nt*16 + n16] = (short)hvb;
      }
    }
    __builtin_amdgcn_wave_barrier();
    const s8v h0 = srd[q];
    const s8v h1 = srd[4+q];
    __builtin_amdgcn_wave_barrier();

    // phase 3: P1/P2 for layer+1 from h' (A-layout)
    #pragma unroll
    for (int nt = 0; nt < 4; ++nt){
      const s8v* wa = (const s8v*)&w1a[(nt*16 + n16)*72];
      const s8v* wb = (const s8v*)&w1b[(nt*16 + n16)*72];
      f32x4 aA = {0.f,0.f,0.f,0.f};
      aA = MFMA16(h0, wa[q],   aA);
      aA = MFMA16(h1, wa[4+q], aA);
      f32x4 aB = {0.f,0.f,0.f,0.f};
      aB = MFMA16(h0, wb[q],   aB);
      aB = MFMA16(h1, wb[4+q], aB);
      const float bb = eb1s[nt*16 + n16];
      #pragma unroll
      for (int r = 0; r < 4; ++r){
        const int o = (t*16 + q*4 + r)*64 + nt*16 + n16;
        P1[o] = f2b(aA[r] + bb);
        P2[o] = f2b(aB[r]);
      }
    }
  }
}

// ---------- launch ----------

extern "C" void kernel_launch(void* const* d_in, const int* in_sizes, int n_in,
                              void* d_out, int out_size, void* d_ws, size_t ws_size,
                              hipStream_t stream)
{
  // Inputs are fp32 (established R4..R12). Read d_in directly.
  const float* x0   = (const float*)d_in[0];
  const int*   z    = (const int*)d_in[1];
  const float* tc   = (const float*)d_in[2];
  const int*   ei   = (const int*)d_in[3];
  const float* embc = (const float*)d_in[4];
  const float* tw1c = (const float*)d_in[5];
  const float* tb1c = (const float*)d_in[6];
  const float* tw2c = (const float*)d_in[7];
  const float* tb2c = (const float*)d_in[8];
  const float* ew1c = (const float*)d_in[9];
  const float* eb1c = (const float*)d_in[10];
  const float* ew2c = (const float*)d_in[11];
  const float* eb2c = (const float*)d_in[12];
  const float* cw1c = (const float*)d_in[13];
  const float* cb1c = (const float*)d_in[14];
  const float* cw2c = (const float*)d_in[15];
  const float* cb2c = (const float*)d_in[16];
  const float* nw1c = (const float*)d_in[17];
  const float* nb1c = (const float*)d_in[18];
  const float* nw2c = (const float*)d_in[19];
  const float* nb2c = (const float*)d_in[20];

  const int N = in_sizes[1];
  const int E = in_sizes[3] / 2;
  const int* srcp = ei;
  const int* dstp = ei + E;

  char* p = (char*)d_ws;
  auto alloc = [&](size_t bytes) -> void* {
    void* r = (void*)p; p += (bytes + 255) & ~(size_t)255; return r;
  };
  unsigned short* hbuf = (unsigned short*)alloc((size_t)N*64*2);
  float* aggf          = (float*)alloc((size_t)N*64*4);     // fp32 (atomic accum)
  unsigned short* P1   = (unsigned short*)alloc((size_t)N*64*2);
  unsigned short* P2   = (unsigned short*)alloc((size_t)N*64*2);
  float* xa            = (float*)alloc((size_t)N*3*4);
  float* xb            = (float*)alloc((size_t)N*3*4);
  float* tmean         = (float*)alloc(64*4);
  int*   degcur        = (int*)alloc((size_t)2*N*4);   // deg | cursor
  int*   deg           = degcur;
  int*   cursor        = degcur + N;
  int*   rowp          = (int*)alloc((size_t)(N+1)*4); // slot-padded prefix
  int*   bsum          = (int*)alloc(256*4);
  int*   csr_src       = (int*)alloc(((size_t)E + 3*(size_t)N + 64)*4);
  int*   slot_meta     = (int*)alloc(((size_t)E/4 + (size_t)N + 16)*4);

  // prologue: tmean + degcur zero in one dispatch
  tmean_zero_kernel<<<512, 256, 0, stream>>>(tc, tw1c, tb1c, tw2c, tb2c,
                                             tmean, degcur, 2*N);
  // fused: h init (hb) + aggf zero + x0->xa copy + layer-0 P1/P2
  init_p12_kernel<<<512, 512, 0, stream>>>(z, embc, tmean, ew1c, eb1c,
                                           hbuf, aggf, P1, P2, x0, xa, N);

  // ---- slot-padded CSR build (once; edges fixed across layers) ----
  hist_kernel<<<(E + 255)/256, 256, 0, stream>>>(dstp, deg, E);
  const int nb = (N + 1023)/1024;
  scan1_kernel<<<nb, 256, 0, stream>>>(deg, rowp, bsum, N);
  scan3_kernel<<<(N + 255)/256, 256, 0, stream>>>(rowp, bsum, deg, N, nb);
  scatter_slot_kernel<<<(E + 255)/256, 256, 0, stream>>>(srcp, dstp, rowp, cursor,
                                                         csr_src, slot_meta, deg, E, N);

  const float* xc = x0;
  float* xnexts[3] = {xa, xb, (float*)d_out};
  for (int l = 0; l < 3; ++l){
    float* xout = xnexts[l];
    edge_tile_kernel<<<1024, 512, 0, stream>>>(rowp, csr_src, slot_meta, xc, xout,
        P1, P2, aggf,
        ew1c, ew2c, eb2c, cw1c, cb1c, cw2c, cb2c, l, (l < 2) ? 1 : 0, N);
    if (l < 2)
      node_p12_kernel<<<512, 512, 0, stream>>>(hbuf, aggf,
          nw1c, nb1c, nw2c, nb2c, ew1c, eb1c, P1, P2,
          xout, xnexts[l+1], l, (l == 0) ? 1 : 0, (l == 0) ? 1 : 0, N);
    xc = xout;
  }
}